// Round 1
// baseline (5370.493 us; speedup 1.0000x reference)
//
#include <hip/hip_runtime.h>
#include <cstdint>
#include <cstddef>

// ============================================================================
// ViT forward, MI355X. Round 0: correct full pipeline, m97-style bf16 GEMMs.
// Workspace layout (bytes):
//   x     f32  8320*768          @ 0          (25,559,040)
//   h     bf16 8320*768          @ 25559040   (12,779,520)
//   qkv   bf16 3*8320*768        @ 38338560   (38,338,560)
//   attn  bf16 8320*768          @ 76677120   (12,779,520)
//   mid   bf16 8320*3072         @ 89456640   (51,118,080)  [aliases patches]
//   wbuf  bf16 7,077,888 elems   @ 140574720  (14,155,776)  per-layer B^T
//   lwt   bf16 768*768           @ 154730496  (1,179,648)
//   TOTAL 155,910,144 B
// ============================================================================

typedef __bf16 bf16x8 __attribute__((ext_vector_type(8)));
typedef float  f32x4  __attribute__((ext_vector_type(4)));

#define DEVINL __device__ __forceinline__

DEVINL float bf2f(uint16_t u){ union U{uint32_t i; float f;} v; v.i=(uint32_t)u<<16; return v.f; }
DEVINL uint16_t f2bf(float f){
  union U{float f; uint32_t i;} v; v.f=f; uint32_t u=v.i;
  return (uint16_t)((u + 0x7fffu + ((u>>16)&1u)) >> 16);   // RNE
}

DEVINL void gl_lds16(const void* g, void* l){
  __builtin_amdgcn_global_load_lds((const __attribute__((address_space(1))) void*)g,
                                   (__attribute__((address_space(3))) void*)l, 16, 0, 0);
}

// ---------------- patchify: images (B,128,128,3) f32 -> patches (8192,768) bf16
__global__ __launch_bounds__(256) void patchify_k(const float* __restrict__ img,
                                                  uint16_t* __restrict__ out){
  int i = blockIdx.x*256 + threadIdx.x;            // 8192*768 = 6,291,456 exact
  int m  = i / 768, kk = i - m*768;
  int b  = m >> 6,  t  = m & 63;
  int py = t >> 3,  px = t & 7;
  int r  = kk / 48, rem = kk - r*48;               // rem = s*3+c (48 contiguous)
  size_t src = ((size_t)(b*128 + py*16 + r)*128 + px*16)*3 + rem;
  out[i] = f2bf(img[src]);
}

// ---------------- 32x32 transpose + f32->bf16 : src (R,C) f32 -> dst (C,R) bf16
DEVINL void tile_transpose(const float* __restrict__ src, uint16_t* __restrict__ dst,
                           int R, int C, int ti, int tj, int tid){
  __shared__ uint16_t tile[32][33];
  int tx = tid & 31, ty = tid >> 5;                // 32 x 8
  int r0 = ti*32, c0 = tj*32;
  #pragma unroll
  for (int i=0;i<4;++i)
    tile[ty+i*8][tx] = f2bf(src[(size_t)(r0+ty+i*8)*C + c0 + tx]);
  __syncthreads();
  #pragma unroll
  for (int i=0;i<4;++i)
    dst[(size_t)(c0+ty+i*8)*R + r0 + tx] = tile[tx][ty+i*8];
}

__global__ __launch_bounds__(256) void transpose_cvt_k(const float* __restrict__ src,
                                                       uint16_t* __restrict__ dst, int R, int C){
  tile_transpose(src, dst, R, C, blockIdx.y, blockIdx.x, threadIdx.x);
}

// one launch per layer: all 6 weights -> wbuf (B^T layout each)
__global__ __launch_bounds__(256) void prep_layer_k(
    const float* __restrict__ Wq, const float* __restrict__ Wk,
    const float* __restrict__ Wv, const float* __restrict__ Wo,
    const float* __restrict__ W1, const float* __restrict__ W2,
    uint16_t* __restrict__ wbuf){
  int idx = blockIdx.x;                            // 6912 tiles total
  const float* src; uint16_t* dst; int R, C, ti, tj;
  if (idx < 2304){                                 // Wq/Wk/Wv/Wo: (768,768)
    int m = idx / 576, t = idx - m*576; ti = t/24; tj = t - ti*24; R=768; C=768;
    src = (m==0)?Wq:(m==1)?Wk:(m==2)?Wv:Wo;
    dst = wbuf + (size_t)m*589824;
  } else if (idx < 4608){                          // W1: (768,3072) -> (3072,768)
    int t = idx - 2304; ti = t/96; tj = t - ti*96; R=768; C=3072;
    src = W1; dst = wbuf + 2359296;
  } else {                                         // W2: (3072,768) -> (768,3072)
    int t = idx - 4608; ti = t/24; tj = t - ti*24; R=3072; C=768;
    src = W2; dst = wbuf + 4718592;
  }
  tile_transpose(src, dst, R, C, ti, tj, threadIdx.x);
}

// ---------------- x[b,0,:] = cls_tok + pos_emb[0]
__global__ __launch_bounds__(256) void cls_init_k(const float* __restrict__ ct,
                                                  const float* __restrict__ pos,
                                                  float* __restrict__ X){
  int b = blockIdx.x, tid = threadIdx.x;
  for (int e = tid; e < 768; e += 256)
    X[(size_t)b*65*768 + e] = ct[e] + pos[e];
}

// ---------------- LayerNorm: x (rows,768) f32 -> h bf16 (two-pass, fp32)
__global__ __launch_bounds__(256) void ln_k(const float* __restrict__ Xin,
                                            uint16_t* __restrict__ H,
                                            const float* __restrict__ g,
                                            const float* __restrict__ b){
  int row = blockIdx.x, tid = threadIdx.x;
  const float* xr = Xin + (size_t)row*768;
  float v0 = xr[tid], v1 = xr[tid+256], v2 = xr[tid+512];
  int wid = tid>>6, lane = tid&63;
  __shared__ float part[4];
  __shared__ float bc[2];
  float s = v0+v1+v2;
  #pragma unroll
  for (int o=32;o;o>>=1) s += __shfl_down(s,o);
  if (lane==0) part[wid] = s;
  __syncthreads();
  if (tid==0) bc[0] = (part[0]+part[1]+part[2]+part[3]) * (1.f/768.f);
  __syncthreads();
  float mu = bc[0];
  float d0=v0-mu, d1=v1-mu, d2=v2-mu;
  float q = d0*d0 + d1*d1 + d2*d2;
  #pragma unroll
  for (int o=32;o;o>>=1) q += __shfl_down(q,o);
  __syncthreads();
  if (lane==0) part[wid] = q;
  __syncthreads();
  if (tid==0) bc[1] = rsqrtf((part[0]+part[1]+part[2]+part[3])*(1.f/768.f) + 1e-5f);
  __syncthreads();
  float rs = bc[1];
  uint16_t* hr = H + (size_t)row*768;
  hr[tid]     = f2bf(d0*rs*g[tid]     + b[tid]);
  hr[tid+256] = f2bf(d1*rs*g[tid+256] + b[tid+256]);
  hr[tid+512] = f2bf(d2*rs*g[tid+512] + b[tid+512]);
}

// ---------------- GEMM: C = A(M,K)bf16 @ Bt(N,K)bf16^T, fp32 acc, epilogues
enum { EP_BF16=0, EP_RES=1, EP_RELU=2, EP_EMB=3 };

template<int MODE>
__global__ __launch_bounds__(256) void gemm_bt_k(
    const uint16_t* __restrict__ A, const uint16_t* __restrict__ Bt,
    int M, int N, int K, int strideB, long long strideO,
    const float* __restrict__ bias, float* __restrict__ X,
    uint16_t* __restrict__ Obf, const float* __restrict__ pos)
{
  __shared__ __align__(16) uint16_t sA[128*32];
  __shared__ __align__(16) uint16_t sB[128*32];
  const int tid = threadIdx.x;
  const int wid = tid>>6, lane = tid&63;
  const int bm = blockIdx.x*128, bn = blockIdx.y*128;
  const int z = blockIdx.z;
  const uint16_t* Bz = Bt + (size_t)z*strideB;
  const int wr = wid>>1, wc = wid&1;               // wave -> 64x64 quadrant
  const int lrow = lane>>2, lk = (lane&3)*8;       // staging lane map
  const int frow = lane&15, fk = (lane>>4)*8;      // MFMA fragment lane map
  f32x4 acc[4][4] = {};
  for (int k0 = 0; k0 < K; k0 += 32){
    __syncthreads();
    #pragma unroll
    for (int rr=0; rr<2; ++rr){
      int row = rr*64 + wid*16 + lrow;
      gl_lds16(A  + (size_t)(bm+row)*K + k0 + lk, (char*)sA + (size_t)(rr*64+wid*16)*64);
      gl_lds16(Bz + (size_t)(bn+row)*K + k0 + lk, (char*)sB + (size_t)(rr*64+wid*16)*64);
    }
    __syncthreads();                               // drains vmcnt before use
    bf16x8 a[4], b[4];
    #pragma unroll
    for (int m=0;m<4;++m) a[m] = *(const bf16x8*)&sA[(wr*64+m*16+frow)*32 + fk];
    #pragma unroll
    for (int n=0;n<4;++n) b[n] = *(const bf16x8*)&sB[(wc*64+n*16+frow)*32 + fk];
    #pragma unroll
    for (int m=0;m<4;++m)
      #pragma unroll
      for (int n=0;n<4;++n)
        acc[m][n] = __builtin_amdgcn_mfma_f32_16x16x32_bf16(a[m], b[n], acc[m][n], 0,0,0);
  }
  uint16_t* Oz = Obf + (size_t)z*(size_t)strideO;
  #pragma unroll
  for (int m=0;m<4;++m){
    int gr0 = bm + wr*64 + m*16 + (lane>>4)*4;     // C/D: col=lane&15, row=(lane>>4)*4+reg
    #pragma unroll
    for (int n=0;n<4;++n){
      int gc = bn + wc*64 + n*16 + (lane&15);
      #pragma unroll
      for (int r=0;r<4;++r){
        int grow = gr0 + r;
        float vsum = acc[m][n][r];
        if constexpr (MODE==EP_BF16){
          Oz[(size_t)grow*N + gc] = f2bf(vsum);
        } else if constexpr (MODE==EP_RES){
          X[(size_t)grow*N + gc] += vsum + bias[gc];
        } else if constexpr (MODE==EP_RELU){
          float u = vsum + bias[gc];
          Oz[(size_t)grow*N + gc] = f2bf(u > 0.f ? u : 0.f);
        } else {                                   // EP_EMB: token remap + pos
          int t = grow & 63, bb = grow >> 6;
          X[((size_t)bb*65 + 1 + t)*768 + gc] = vsum + pos[(size_t)(t+1)*768 + gc];
        }
      }
    }
  }
}

// ---------------- attention: one block per (b,head); fp32 softmax
__global__ __launch_bounds__(256) void attn_k(const uint16_t* __restrict__ q,
    const uint16_t* __restrict__ k, const uint16_t* __restrict__ v,
    uint16_t* __restrict__ o){
  __shared__ float Qs[65][65];                     // pad 65 -> conflict-free
  __shared__ float Ks[65][65];
  __shared__ float Vs[65][65];
  int bh = blockIdx.x; int b = bh / 12, hd = bh - b*12;
  int tid = threadIdx.x;
  size_t base = (size_t)b*65*768 + (size_t)hd*64;
  for (int i = tid; i < 65*64; i += 256){
    int t = i >> 6, d = i & 63;
    size_t s = base + (size_t)t*768 + d;
    Qs[t][d] = bf2f(q[s]);
    Ks[t][d] = bf2f(k[s]);
    Vs[t][d] = bf2f(v[s]);
  }
  __syncthreads();
  int wid = tid>>6, lane = tid&63;
  const float scale = 0.03608439182435161f;        // 768^-0.5 (reference uses E!)
  for (int t = wid; t < 65; t += 4){
    const float* Qt = Qs[t];
    const float* Kj = Ks[lane];
    float s0 = 0.f;
    #pragma unroll 16
    for (int d=0; d<64; ++d) s0 += Qt[d]*Kj[d];    // lane = key j
    s0 *= scale;
    float sp = Qt[lane] * Ks[64][lane];            // key j=64 via wave reduce
    #pragma unroll
    for (int off=32; off; off>>=1) sp += __shfl_down(sp, off);
    float s64 = __shfl(sp, 0) * scale;
    float mx = s0;
    #pragma unroll
    for (int off=32; off; off>>=1) mx = fmaxf(mx, __shfl_xor(mx, off));
    mx = fmaxf(mx, s64);
    float p0  = __expf(s0 - mx);
    float p64 = __expf(s64 - mx);
    float sum = p0;
    #pragma unroll
    for (int off=32; off; off>>=1) sum += __shfl_xor(sum, off);
    sum += p64;
    float rinv = 1.f / sum;
    p0 *= rinv; p64 *= rinv;
    float oa = p64 * Vs[64][lane];                 // lane = d now
    for (int j=0;j<64;++j)
      oa += __shfl(p0, j) * Vs[j][lane];
    o[base + (size_t)t*768 + lane] = f2bf(oa);
  }
}

// ---------------- head: logits = cls @ head_w + b, softmax (all fp32)
__global__ __launch_bounds__(256) void head_k(const float* __restrict__ X,
    const float* __restrict__ W, const float* __restrict__ bias,
    float* __restrict__ out){
  int b = blockIdx.x, a = threadIdx.x;             // a in [0,256)
  const float* xr = X + (size_t)b*65*768;          // cls row
  float acc = bias[a];
  for (int kk=0; kk<768; ++kk) acc += xr[kk]*W[(size_t)kk*256 + a];
  int wid = a>>6, lane = a&63;
  __shared__ float red[4];
  float mx = acc;
  #pragma unroll
  for (int off=32; off; off>>=1) mx = fmaxf(mx, __shfl_xor(mx, off));
  if (lane==0) red[wid]=mx;
  __syncthreads();
  mx = fmaxf(fmaxf(red[0],red[1]), fmaxf(red[2],red[3]));
  float e = __expf(acc-mx);
  float s = e;
  #pragma unroll
  for (int off=32; off; off>>=1) s += __shfl_xor(s, off);
  __syncthreads();
  if (lane==0) red[wid]=s;
  __syncthreads();
  s = red[0]+red[1]+red[2]+red[3];
  out[(size_t)b*256 + a] = e/s;
}

// ============================================================================
extern "C" void kernel_launch(void* const* d_in, const int* in_sizes, int n_in,
                              void* d_out, int out_size, void* d_ws, size_t ws_size,
                              hipStream_t stream)
{
  const float* images = (const float*)d_in[0];
  const float* lin_w  = (const float*)d_in[1];
  const float* cls_tok= (const float*)d_in[2];
  const float* pos    = (const float*)d_in[3];
  const float* Wq = (const float*)d_in[4];
  const float* Wk = (const float*)d_in[5];
  const float* Wv = (const float*)d_in[6];
  const float* Wo = (const float*)d_in[7];
  const float* bo = (const float*)d_in[8];
  const float* ln1g=(const float*)d_in[9];
  const float* ln1b=(const float*)d_in[10];
  const float* ln2g=(const float*)d_in[11];
  const float* ln2b=(const float*)d_in[12];
  const float* W1 = (const float*)d_in[13];
  const float* b1 = (const float*)d_in[14];
  const float* W2 = (const float*)d_in[15];
  const float* b2 = (const float*)d_in[16];
  const float* hw = (const float*)d_in[17];
  const float* hb = (const float*)d_in[18];

  char* ws = (char*)d_ws;
  float*    x    = (float*)   (ws + 0);
  uint16_t* h    = (uint16_t*)(ws + 25559040);
  uint16_t* qkv  = (uint16_t*)(ws + 38338560);
  uint16_t* attn = (uint16_t*)(ws + 76677120);
  uint16_t* mid  = (uint16_t*)(ws + 89456640);     // patches alias
  uint16_t* wbuf = (uint16_t*)(ws + 140574720);
  uint16_t* lwt  = (uint16_t*)(ws + 154730496);

  // embed
  patchify_k<<<24576,256,0,stream>>>(images, mid);
  transpose_cvt_k<<<dim3(24,24),256,0,stream>>>(lin_w, lwt, 768, 768);
  gemm_bt_k<EP_EMB><<<dim3(64,6,1),256,0,stream>>>(mid, lwt, 8192,768,768, 0,0,
                                                   nullptr, x, nullptr, pos);
  cls_init_k<<<128,256,0,stream>>>(cls_tok, pos, x);

  for (int l=0;l<12;++l){
    prep_layer_k<<<6912,256,0,stream>>>(Wq+(size_t)l*589824, Wk+(size_t)l*589824,
                                        Wv+(size_t)l*589824, Wo+(size_t)l*589824,
                                        W1+(size_t)l*2359296, W2+(size_t)l*2359296, wbuf);
    ln_k<<<8320,256,0,stream>>>(x, h, ln1g+(size_t)l*768, ln1b+(size_t)l*768);
    gemm_bt_k<EP_BF16><<<dim3(65,6,3),256,0,stream>>>(h, wbuf, 8320,768,768,
                                                      589824, 6389760LL,
                                                      nullptr, nullptr, qkv, nullptr);
    attn_k<<<1536,256,0,stream>>>(qkv, qkv+6389760, qkv+12779520, attn);
    gemm_bt_k<EP_RES><<<dim3(65,6,1),256,0,stream>>>(attn, wbuf+1769472, 8320,768,768,
                                                     0,0, bo+(size_t)l*768, x, nullptr, nullptr);
    ln_k<<<8320,256,0,stream>>>(x, h, ln2g+(size_t)l*768, ln2b+(size_t)l*768);
    gemm_bt_k<EP_RELU><<<dim3(65,24,1),256,0,stream>>>(h, wbuf+2359296, 8320,3072,768,
                                                       0,0, b1+(size_t)l*3072, nullptr, mid, nullptr);
    gemm_bt_k<EP_RES><<<dim3(65,6,1),256,0,stream>>>(mid, wbuf+4718592, 8320,768,3072,
                                                     0,0, b2+(size_t)l*768, x, nullptr, nullptr);
  }
  head_k<<<128,256,0,stream>>>(x, hw, hb, (float*)d_out);
}

// Round 2
// 3913.075 us; speedup vs baseline: 1.3724x; 1.3724x over previous
//
#include <hip/hip_runtime.h>
#include <cstdint>
#include <cstddef>

// ============================================================================
// ViT forward, MI355X. Round 1: MFMA attention (was 157us/layer VALU-serial).
// Workspace layout (bytes):
//   x     f32  8320*768          @ 0          (25,559,040)
//   h     bf16 8320*768          @ 25559040   (12,779,520)
//   qkv   bf16 3*8320*768        @ 38338560   (38,338,560)
//   attn  bf16 8320*768          @ 76677120   (12,779,520)
//   mid   bf16 8320*3072         @ 89456640   (51,118,080)  [aliases patches]
//   wbuf  bf16 7,077,888 elems   @ 140574720  (14,155,776)  per-layer B^T
//   lwt   bf16 768*768           @ 154730496  (1,179,648)
//   TOTAL 155,910,144 B
// ============================================================================

typedef __bf16 bf16x8 __attribute__((ext_vector_type(8)));
typedef float  f32x4  __attribute__((ext_vector_type(4)));

#define DEVINL __device__ __forceinline__

DEVINL uint16_t f2bf(float f){
  union U{float f; uint32_t i;} v; v.f=f; uint32_t u=v.i;
  return (uint16_t)((u + 0x7fffu + ((u>>16)&1u)) >> 16);   // RNE
}

DEVINL void gl_lds16(const void* g, void* l){
  __builtin_amdgcn_global_load_lds((const __attribute__((address_space(1))) void*)g,
                                   (__attribute__((address_space(3))) void*)l, 16, 0, 0);
}

// ---------------- patchify: images (B,128,128,3) f32 -> patches (8192,768) bf16
__global__ __launch_bounds__(256) void patchify_k(const float* __restrict__ img,
                                                  uint16_t* __restrict__ out){
  int i = blockIdx.x*256 + threadIdx.x;            // 8192*768 = 6,291,456 exact
  int m  = i / 768, kk = i - m*768;
  int b  = m >> 6,  t  = m & 63;
  int py = t >> 3,  px = t & 7;
  int r  = kk / 48, rem = kk - r*48;               // rem = s*3+c (48 contiguous)
  size_t src = ((size_t)(b*128 + py*16 + r)*128 + px*16)*3 + rem;
  out[i] = f2bf(img[src]);
}

// ---------------- 32x32 transpose + f32->bf16 : src (R,C) f32 -> dst (C,R) bf16
DEVINL void tile_transpose(const float* __restrict__ src, uint16_t* __restrict__ dst,
                           int R, int C, int ti, int tj, int tid){
  __shared__ uint16_t tile[32][33];
  int tx = tid & 31, ty = tid >> 5;                // 32 x 8
  int r0 = ti*32, c0 = tj*32;
  #pragma unroll
  for (int i=0;i<4;++i)
    tile[ty+i*8][tx] = f2bf(src[(size_t)(r0+ty+i*8)*C + c0 + tx]);
  __syncthreads();
  #pragma unroll
  for (int i=0;i<4;++i)
    dst[(size_t)(c0+ty+i*8)*R + r0 + tx] = tile[tx][ty+i*8];
}

__global__ __launch_bounds__(256) void transpose_cvt_k(const float* __restrict__ src,
                                                       uint16_t* __restrict__ dst, int R, int C){
  tile_transpose(src, dst, R, C, blockIdx.y, blockIdx.x, threadIdx.x);
}

// one launch per layer: all 6 weights -> wbuf (B^T layout each)
__global__ __launch_bounds__(256) void prep_layer_k(
    const float* __restrict__ Wq, const float* __restrict__ Wk,
    const float* __restrict__ Wv, const float* __restrict__ Wo,
    const float* __restrict__ W1, const float* __restrict__ W2,
    uint16_t* __restrict__ wbuf){
  int idx = blockIdx.x;                            // 6912 tiles total
  const float* src; uint16_t* dst; int R, C, ti, tj;
  if (idx < 2304){                                 // Wq/Wk/Wv/Wo: (768,768)
    int m = idx / 576, t = idx - m*576; ti = t/24; tj = t - ti*24; R=768; C=768;
    src = (m==0)?Wq:(m==1)?Wk:(m==2)?Wv:Wo;
    dst = wbuf + (size_t)m*589824;
  } else if (idx < 4608){                          // W1: (768,3072) -> (3072,768)
    int t = idx - 2304; ti = t/96; tj = t - ti*96; R=768; C=3072;
    src = W1; dst = wbuf + 2359296;
  } else {                                         // W2: (3072,768) -> (768,3072)
    int t = idx - 4608; ti = t/24; tj = t - ti*24; R=3072; C=768;
    src = W2; dst = wbuf + 4718592;
  }
  tile_transpose(src, dst, R, C, ti, tj, threadIdx.x);
}

// ---------------- x[b,0,:] = cls_tok + pos_emb[0]
__global__ __launch_bounds__(256) void cls_init_k(const float* __restrict__ ct,
                                                  const float* __restrict__ pos,
                                                  float* __restrict__ X){
  int b = blockIdx.x, tid = threadIdx.x;
  for (int e = tid; e < 768; e += 256)
    X[(size_t)b*65*768 + e] = ct[e] + pos[e];
}

// ---------------- LayerNorm: x (rows,768) f32 -> h bf16 (two-pass, fp32)
__global__ __launch_bounds__(256) void ln_k(const float* __restrict__ Xin,
                                            uint16_t* __restrict__ H,
                                            const float* __restrict__ g,
                                            const float* __restrict__ b){
  int row = blockIdx.x, tid = threadIdx.x;
  const float* xr = Xin + (size_t)row*768;
  float v0 = xr[tid], v1 = xr[tid+256], v2 = xr[tid+512];
  int wid = tid>>6, lane = tid&63;
  __shared__ float part[4];
  __shared__ float bc[2];
  float s = v0+v1+v2;
  #pragma unroll
  for (int o=32;o;o>>=1) s += __shfl_down(s,o);
  if (lane==0) part[wid] = s;
  __syncthreads();
  if (tid==0) bc[0] = (part[0]+part[1]+part[2]+part[3]) * (1.f/768.f);
  __syncthreads();
  float mu = bc[0];
  float d0=v0-mu, d1=v1-mu, d2=v2-mu;
  float q = d0*d0 + d1*d1 + d2*d2;
  #pragma unroll
  for (int o=32;o;o>>=1) q += __shfl_down(q,o);
  __syncthreads();
  if (lane==0) part[wid] = q;
  __syncthreads();
  if (tid==0) bc[1] = rsqrtf((part[0]+part[1]+part[2]+part[3])*(1.f/768.f) + 1e-5f);
  __syncthreads();
  float rs = bc[1];
  uint16_t* hr = H + (size_t)row*768;
  hr[tid]     = f2bf(d0*rs*g[tid]     + b[tid]);
  hr[tid+256] = f2bf(d1*rs*g[tid+256] + b[tid+256]);
  hr[tid+512] = f2bf(d2*rs*g[tid+512] + b[tid+512]);
}

// ---------------- GEMM: C = A(M,K)bf16 @ Bt(N,K)bf16^T, fp32 acc, epilogues
enum { EP_BF16=0, EP_RES=1, EP_RELU=2, EP_EMB=3 };

template<int MODE>
__global__ __launch_bounds__(256) void gemm_bt_k(
    const uint16_t* __restrict__ A, const uint16_t* __restrict__ Bt,
    int M, int N, int K, int strideB, long long strideO,
    const float* __restrict__ bias, float* __restrict__ X,
    uint16_t* __restrict__ Obf, const float* __restrict__ pos)
{
  __shared__ __align__(16) uint16_t sA[128*32];
  __shared__ __align__(16) uint16_t sB[128*32];
  const int tid = threadIdx.x;
  const int wid = tid>>6, lane = tid&63;
  const int bm = blockIdx.x*128, bn = blockIdx.y*128;
  const int z = blockIdx.z;
  const uint16_t* Bz = Bt + (size_t)z*strideB;
  const int wr = wid>>1, wc = wid&1;               // wave -> 64x64 quadrant
  const int lrow = lane>>2, lk = (lane&3)*8;       // staging lane map
  const int frow = lane&15, fk = (lane>>4)*8;      // MFMA fragment lane map
  f32x4 acc[4][4] = {};
  for (int k0 = 0; k0 < K; k0 += 32){
    __syncthreads();
    #pragma unroll
    for (int rr=0; rr<2; ++rr){
      int row = rr*64 + wid*16 + lrow;
      gl_lds16(A  + (size_t)(bm+row)*K + k0 + lk, (char*)sA + (size_t)(rr*64+wid*16)*64);
      gl_lds16(Bz + (size_t)(bn+row)*K + k0 + lk, (char*)sB + (size_t)(rr*64+wid*16)*64);
    }
    __syncthreads();                               // drains vmcnt before use
    bf16x8 a[4], b[4];
    #pragma unroll
    for (int m=0;m<4;++m) a[m] = *(const bf16x8*)&sA[(wr*64+m*16+frow)*32 + fk];
    #pragma unroll
    for (int n=0;n<4;++n) b[n] = *(const bf16x8*)&sB[(wc*64+n*16+frow)*32 + fk];
    #pragma unroll
    for (int m=0;m<4;++m)
      #pragma unroll
      for (int n=0;n<4;++n)
        acc[m][n] = __builtin_amdgcn_mfma_f32_16x16x32_bf16(a[m], b[n], acc[m][n], 0,0,0);
  }
  uint16_t* Oz = Obf + (size_t)z*(size_t)strideO;
  #pragma unroll
  for (int m=0;m<4;++m){
    int gr0 = bm + wr*64 + m*16 + (lane>>4)*4;     // C/D: col=lane&15, row=(lane>>4)*4+reg
    #pragma unroll
    for (int n=0;n<4;++n){
      int gc = bn + wc*64 + n*16 + (lane&15);
      #pragma unroll
      for (int r=0;r<4;++r){
        int grow = gr0 + r;
        float vsum = acc[m][n][r];
        if constexpr (MODE==EP_BF16){
          Oz[(size_t)grow*N + gc] = f2bf(vsum);
        } else if constexpr (MODE==EP_RES){
          X[(size_t)grow*N + gc] += vsum + bias[gc];
        } else if constexpr (MODE==EP_RELU){
          float u = vsum + bias[gc];
          Oz[(size_t)grow*N + gc] = f2bf(u > 0.f ? u : 0.f);
        } else {                                   // EP_EMB: token remap + pos
          int t = grow & 63, bb = grow >> 6;
          X[((size_t)bb*65 + 1 + t)*768 + gc] = vsum + pos[(size_t)(t+1)*768 + gc];
        }
      }
    }
  }
}

// ---------------- MFMA attention: one block (5 waves) per (b,head)
// S = Q K^T via mfma_16x16x32 (A=Q from global, B=K from global — K rows are
// already B^T layout). Softmax fully in-register on the C/D fragment
// (row r lives in a 16-lane group; reduce via shfl_xor 1/2/4/8). P -> LDS
// bf16 (stride 104: row-bank period 8 -> 2-way = free). V transposed to LDS
// once per block. O = P V via 60 more MFMAs. Wave w owns query tile m=w.
__global__ __launch_bounds__(320) void attn_mfma_k(const uint16_t* __restrict__ q,
    const uint16_t* __restrict__ k, const uint16_t* __restrict__ v,
    uint16_t* __restrict__ o)
{
  __shared__ __align__(16) uint16_t P_lds[80][104];  // queries x keys (pad 96+8)
  __shared__ __align__(16) uint16_t Vt[64][104];     // d x keys
  const int bh = blockIdx.x; const int b = bh / 12, hd = bh - b*12;
  const int tid = threadIdx.x;
  const int m = tid>>6;                              // wave id == query tile
  const int lane = tid&63;
  const int g = lane>>4, c = lane&15;
  const size_t base = (size_t)b*65*768 + (size_t)hd*64;

  // ---- zero LDS padding (keys >= 80 in P; keys 64..95 in Vt)
  for (int i = tid; i < 80*16; i += 320) P_lds[i>>4][80 + (i&15)] = 0;
  for (int i = tid; i < 64*32; i += 320) Vt[i>>5][64 + (i&31)] = 0;
  __syncthreads();
  // ---- transpose V into Vt: 65 keys x 8 d-chunks
  for (int j = tid; j < 520; j += 320){
    int key = j >> 3, dc = j & 7;
    union { bf16x8 v8; uint16_t u[8]; } gv;
    gv.v8 = *(const bf16x8*)&v[base + (size_t)key*768 + dc*8];
    #pragma unroll
    for (int e = 0; e < 8; ++e) Vt[dc*8 + e][key] = gv.u[e];
  }

  // ---- K fragments (B-operand: row = key = n*16+c, k-chunk = g*8)
  bf16x8 bk[5][2];
  #pragma unroll
  for (int n=0;n<5;++n)
    #pragma unroll
    for (int kk=0;kk<2;++kk)
      bk[n][kk] = *(const bf16x8*)&k[base + (size_t)(n*16 + c)*768 + kk*32 + g*8];

  // ---- S = Q K^T for this wave's query tile
  bf16x8 aq[2];
  #pragma unroll
  for (int kk=0;kk<2;++kk)
    aq[kk] = *(const bf16x8*)&q[base + (size_t)(m*16 + c)*768 + kk*32 + g*8];
  f32x4 sacc[5] = {};
  #pragma unroll
  for (int kk=0;kk<2;++kk)
    #pragma unroll
    for (int n=0;n<5;++n)
      sacc[n] = __builtin_amdgcn_mfma_f32_16x16x32_bf16(aq[kk], bk[n][kk], sacc[n], 0,0,0);

  // ---- in-register softmax (per output row r; 16-lane-group reduce)
  const float scale = 0.03608439182435161f;          // 768^-0.5
  #pragma unroll
  for (int r=0;r<4;++r){
    float val[5]; float mx = -3.0e38f;
    #pragma unroll
    for (int n=0;n<5;++n){
      val[n] = (n*16 + c) < 65 ? sacc[n][r]*scale : -3.0e38f;
      mx = fmaxf(mx, val[n]);
    }
    #pragma unroll
    for (int off=1; off<16; off<<=1) mx = fmaxf(mx, __shfl_xor(mx, off));
    float p[5], sum = 0.f;
    #pragma unroll
    for (int n=0;n<5;++n){
      p[n] = (n*16 + c) < 65 ? __expf(val[n]-mx) : 0.f;
      sum += p[n];
    }
    #pragma unroll
    for (int off=1; off<16; off<<=1) sum += __shfl_xor(sum, off);
    float rinv = 1.f / sum;
    int row = m*16 + g*4 + r;
    #pragma unroll
    for (int n=0;n<5;++n) P_lds[row][n*16 + c] = f2bf(p[n]*rinv);
  }
  __syncthreads();                                   // P + Vt ready

  // ---- O = P V  (A = P rows=query k=key; B = Vt rows=d k=key)
  bf16x8 vb[4][3];
  #pragma unroll
  for (int n=0;n<4;++n)
    #pragma unroll
    for (int kk=0;kk<3;++kk)
      vb[n][kk] = *(const bf16x8*)&Vt[n*16 + c][kk*32 + g*8];
  f32x4 oacc[4] = {};
  #pragma unroll
  for (int kk=0;kk<3;++kk){
    bf16x8 pa = *(const bf16x8*)&P_lds[m*16 + c][kk*32 + g*8];
    #pragma unroll
    for (int n=0;n<4;++n)
      oacc[n] = __builtin_amdgcn_mfma_f32_16x16x32_bf16(pa, vb[n][kk], oacc[n], 0,0,0);
  }
  #pragma unroll
  for (int r=0;r<4;++r){
    int row = m*16 + g*4 + r;
    if (row < 65){
      #pragma unroll
      for (int n=0;n<4;++n)
        o[base + (size_t)row*768 + n*16 + c] = f2bf(oacc[n][r]);
    }
  }
}

// ---------------- head: logits = cls @ head_w + b, softmax (all fp32)
__global__ __launch_bounds__(256) void head_k(const float* __restrict__ X,
    const float* __restrict__ W, const float* __restrict__ bias,
    float* __restrict__ out){
  int b = blockIdx.x, a = threadIdx.x;             // a in [0,256)
  const float* xr = X + (size_t)b*65*768;          // cls row
  float acc = bias[a];
  for (int kk=0; kk<768; ++kk) acc += xr[kk]*W[(size_t)kk*256 + a];
  int wid = a>>6, lane = a&63;
  __shared__ float red[4];
  float mx = acc;
  #pragma unroll
  for (int off=32; off; off>>=1) mx = fmaxf(mx, __shfl_xor(mx, off));
  if (lane==0) red[wid]=mx;
  __syncthreads();
  mx = fmaxf(fmaxf(red[0],red[1]), fmaxf(red[2],red[3]));
  float e = __expf(acc-mx);
  float s = e;
  #pragma unroll
  for (int off=32; off; off>>=1) s += __shfl_xor(s, off);
  __syncthreads();
  if (lane==0) red[wid]=s;
  __syncthreads();
  s = red[0]+red[1]+red[2]+red[3];
  out[(size_t)b*256 + a] = e/s;
}

// ============================================================================
extern "C" void kernel_launch(void* const* d_in, const int* in_sizes, int n_in,
                              void* d_out, int out_size, void* d_ws, size_t ws_size,
                              hipStream_t stream)
{
  const float* images = (const float*)d_in[0];
  const float* lin_w  = (const float*)d_in[1];
  const float* cls_tok= (const float*)d_in[2];
  const float* pos    = (const float*)d_in[3];
  const float* Wq = (const float*)d_in[4];
  const float* Wk = (const float*)d_in[5];
  const float* Wv = (const float*)d_in[6];
  const float* Wo = (const float*)d_in[7];
  const float* bo = (const float*)d_in[8];
  const float* ln1g=(const float*)d_in[9];
  const float* ln1b=(const float*)d_in[10];
  const float* ln2g=(const float*)d_in[11];
  const float* ln2b=(const float*)d_in[12];
  const float* W1 = (const float*)d_in[13];
  const float* b1 = (const float*)d_in[14];
  const float* W2 = (const float*)d_in[15];
  const float* b2 = (const float*)d_in[16];
  const float* hw = (const float*)d_in[17];
  const float* hb = (const float*)d_in[18];

  char* ws = (char*)d_ws;
  float*    x    = (float*)   (ws + 0);
  uint16_t* h    = (uint16_t*)(ws + 25559040);
  uint16_t* qkv  = (uint16_t*)(ws + 38338560);
  uint16_t* attn = (uint16_t*)(ws + 76677120);
  uint16_t* mid  = (uint16_t*)(ws + 89456640);     // patches alias
  uint16_t* wbuf = (uint16_t*)(ws + 140574720);
  uint16_t* lwt  = (uint16_t*)(ws + 154730496);

  // embed
  patchify_k<<<24576,256,0,stream>>>(images, mid);
  transpose_cvt_k<<<dim3(24,24),256,0,stream>>>(lin_w, lwt, 768, 768);
  gemm_bt_k<EP_EMB><<<dim3(64,6,1),256,0,stream>>>(mid, lwt, 8192,768,768, 0,0,
                                                   nullptr, x, nullptr, pos);
  cls_init_k<<<128,256,0,stream>>>(cls_tok, pos, x);

  for (int l=0;l<12;++l){
    prep_layer_k<<<6912,256,0,stream>>>(Wq+(size_t)l*589824, Wk+(size_t)l*589824,
                                        Wv+(size_t)l*589824, Wo+(size_t)l*589824,
                                        W1+(size_t)l*2359296, W2+(size_t)l*2359296, wbuf);
    ln_k<<<8320,256,0,stream>>>(x, h, ln1g+(size_t)l*768, ln1b+(size_t)l*768);
    gemm_bt_k<EP_BF16><<<dim3(65,6,3),256,0,stream>>>(h, wbuf, 8320,768,768,
                                                      589824, 6389760LL,
                                                      nullptr, nullptr, qkv, nullptr);
    attn_mfma_k<<<1536,320,0,stream>>>(qkv, qkv+6389760, qkv+12779520, attn);
    gemm_bt_k<EP_RES><<<dim3(65,6,1),256,0,stream>>>(attn, wbuf+1769472, 8320,768,768,
                                                     0,0, bo+(size_t)l*768, x, nullptr, nullptr);
    ln_k<<<8320,256,0,stream>>>(x, h, ln2g+(size_t)l*768, ln2b+(size_t)l*768);
    gemm_bt_k<EP_RELU><<<dim3(65,24,1),256,0,stream>>>(h, wbuf+2359296, 8320,3072,768,
                                                       0,0, b1+(size_t)l*3072, nullptr, mid, nullptr);
    gemm_bt_k<EP_RES><<<dim3(65,6,1),256,0,stream>>>(mid, wbuf+4718592, 8320,768,3072,
                                                     0,0, b2+(size_t)l*768, x, nullptr, nullptr);
  }
  head_k<<<128,256,0,stream>>>(x, hw, hb, (float*)d_out);
}

// Round 3
// 3551.476 us; speedup vs baseline: 1.5122x; 1.1018x over previous
//
#include <hip/hip_runtime.h>
#include <cstdint>
#include <cstddef>

// ============================================================================
// ViT forward, MI355X. Round 2: GEMM double-buffer prefetch (counted vmcnt,
// raw s_barrier), granule-swizzled LDS (bank-conflict fix), N-fastest grid.
// Workspace layout (bytes):
//   x     f32  8320*768          @ 0          (25,559,040)
//   h     bf16 8320*768          @ 25559040   (12,779,520)
//   qkv   bf16 3*8320*768        @ 38338560   (38,338,560)
//   attn  bf16 8320*768          @ 76677120   (12,779,520)
//   mid   bf16 8320*3072         @ 89456640   (51,118,080)  [aliases patches]
//   wbuf  bf16 7,077,888 elems   @ 140574720  (14,155,776)  per-layer B^T
//   lwt   bf16 768*768           @ 154730496  (1,179,648)
//   TOTAL 155,910,144 B
// ============================================================================

typedef __bf16 bf16x8 __attribute__((ext_vector_type(8)));
typedef float  f32x4  __attribute__((ext_vector_type(4)));

#define DEVINL __device__ __forceinline__

DEVINL uint16_t f2bf(float f){
  union U{float f; uint32_t i;} v; v.f=f; uint32_t u=v.i;
  return (uint16_t)((u + 0x7fffu + ((u>>16)&1u)) >> 16);   // RNE
}

DEVINL void gl_lds16(const void* g, void* l){
  __builtin_amdgcn_global_load_lds((const __attribute__((address_space(1))) void*)g,
                                   (__attribute__((address_space(3))) void*)l, 16, 0, 0);
}

// ---------------- patchify: images (B,128,128,3) f32 -> patches (8192,768) bf16
__global__ __launch_bounds__(256) void patchify_k(const float* __restrict__ img,
                                                  uint16_t* __restrict__ out){
  int i = blockIdx.x*256 + threadIdx.x;            // 8192*768 = 6,291,456 exact
  int m  = i / 768, kk = i - m*768;
  int b  = m >> 6,  t  = m & 63;
  int py = t >> 3,  px = t & 7;
  int r  = kk / 48, rem = kk - r*48;               // rem = s*3+c (48 contiguous)
  size_t src = ((size_t)(b*128 + py*16 + r)*128 + px*16)*3 + rem;
  out[i] = f2bf(img[src]);
}

// ---------------- 32x32 transpose + f32->bf16 : src (R,C) f32 -> dst (C,R) bf16
DEVINL void tile_transpose(const float* __restrict__ src, uint16_t* __restrict__ dst,
                           int R, int C, int ti, int tj, int tid){
  __shared__ uint16_t tile[32][33];
  int tx = tid & 31, ty = tid >> 5;                // 32 x 8
  int r0 = ti*32, c0 = tj*32;
  #pragma unroll
  for (int i=0;i<4;++i)
    tile[ty+i*8][tx] = f2bf(src[(size_t)(r0+ty+i*8)*C + c0 + tx]);
  __syncthreads();
  #pragma unroll
  for (int i=0;i<4;++i)
    dst[(size_t)(c0+ty+i*8)*R + r0 + tx] = tile[tx][ty+i*8];
}

__global__ __launch_bounds__(256) void transpose_cvt_k(const float* __restrict__ src,
                                                       uint16_t* __restrict__ dst, int R, int C){
  tile_transpose(src, dst, R, C, blockIdx.y, blockIdx.x, threadIdx.x);
}

// one launch per layer: all 6 weights -> wbuf (B^T layout each)
__global__ __launch_bounds__(256) void prep_layer_k(
    const float* __restrict__ Wq, const float* __restrict__ Wk,
    const float* __restrict__ Wv, const float* __restrict__ Wo,
    const float* __restrict__ W1, const float* __restrict__ W2,
    uint16_t* __restrict__ wbuf){
  int idx = blockIdx.x;                            // 6912 tiles total
  const float* src; uint16_t* dst; int R, C, ti, tj;
  if (idx < 2304){                                 // Wq/Wk/Wv/Wo: (768,768)
    int m = idx / 576, t = idx - m*576; ti = t/24; tj = t - ti*24; R=768; C=768;
    src = (m==0)?Wq:(m==1)?Wk:(m==2)?Wv:Wo;
    dst = wbuf + (size_t)m*589824;
  } else if (idx < 4608){                          // W1: (768,3072) -> (3072,768)
    int t = idx - 2304; ti = t/96; tj = t - ti*96; R=768; C=3072;
    src = W1; dst = wbuf + 2359296;
  } else {                                         // W2: (3072,768) -> (768,3072)
    int t = idx - 4608; ti = t/24; tj = t - ti*24; R=3072; C=768;
    src = W2; dst = wbuf + 4718592;
  }
  tile_transpose(src, dst, R, C, ti, tj, threadIdx.x);
}

// ---------------- x[b,0,:] = cls_tok + pos_emb[0]
__global__ __launch_bounds__(256) void cls_init_k(const float* __restrict__ ct,
                                                  const float* __restrict__ pos,
                                                  float* __restrict__ X){
  int b = blockIdx.x, tid = threadIdx.x;
  for (int e = tid; e < 768; e += 256)
    X[(size_t)b*65*768 + e] = ct[e] + pos[e];
}

// ---------------- LayerNorm: x (rows,768) f32 -> h bf16 (two-pass, fp32)
__global__ __launch_bounds__(256) void ln_k(const float* __restrict__ Xin,
                                            uint16_t* __restrict__ H,
                                            const float* __restrict__ g,
                                            const float* __restrict__ b){
  int row = blockIdx.x, tid = threadIdx.x;
  const float* xr = Xin + (size_t)row*768;
  float v0 = xr[tid], v1 = xr[tid+256], v2 = xr[tid+512];
  int wid = tid>>6, lane = tid&63;
  __shared__ float part[4];
  __shared__ float bc[2];
  float s = v0+v1+v2;
  #pragma unroll
  for (int o=32;o;o>>=1) s += __shfl_down(s,o);
  if (lane==0) part[wid] = s;
  __syncthreads();
  if (tid==0) bc[0] = (part[0]+part[1]+part[2]+part[3]) * (1.f/768.f);
  __syncthreads();
  float mu = bc[0];
  float d0=v0-mu, d1=v1-mu, d2=v2-mu;
  float q = d0*d0 + d1*d1 + d2*d2;
  #pragma unroll
  for (int o=32;o;o>>=1) q += __shfl_down(q,o);
  __syncthreads();
  if (lane==0) part[wid] = q;
  __syncthreads();
  if (tid==0) bc[1] = rsqrtf((part[0]+part[1]+part[2]+part[3])*(1.f/768.f) + 1e-5f);
  __syncthreads();
  float rs = bc[1];
  uint16_t* hr = H + (size_t)row*768;
  hr[tid]     = f2bf(d0*rs*g[tid]     + b[tid]);
  hr[tid+256] = f2bf(d1*rs*g[tid+256] + b[tid+256]);
  hr[tid+512] = f2bf(d2*rs*g[tid+512] + b[tid+512]);
}

// ---------------- GEMM: C = A(M,K)bf16 @ Bt(N,K)bf16^T, fp32 acc, epilogues
// Double-buffered LDS with prefetch: STAGE(t+1) issued before compute(t);
// counted vmcnt(4) + raw s_barrier (avoids compiler's full vmcnt(0) drain).
// LDS granule swizzle: granule G holds (row=G>>2, chunk=((G&3)-(row>>1))&3)
// so fragment ds_read_b128 spreads over 8 bank-groups (was 2 -> 8-way).
enum { EP_BF16=0, EP_RES=1, EP_RELU=2, EP_EMB=3 };

template<int MODE>
__global__ __launch_bounds__(256) void gemm_bt_k(
    const uint16_t* __restrict__ A, const uint16_t* __restrict__ Bt,
    int M, int N, int K, int strideB, long long strideO,
    const float* __restrict__ bias, float* __restrict__ X,
    uint16_t* __restrict__ Obf, const float* __restrict__ pos)
{
  __shared__ __align__(16) uint16_t sA[2][128*32];
  __shared__ __align__(16) uint16_t sB[2][128*32];
  const int tid = threadIdx.x;
  const int wid = tid>>6, lane = tid&63;
  const int bn = blockIdx.x*128, bm = blockIdx.y*128;   // N fastest: A-panel reuse
  const int z = blockIdx.z;
  const uint16_t* Bz = Bt + (size_t)z*strideB;
  const int wr = wid>>1, wc = wid&1;               // wave -> 64x64 quadrant
  const int frow = lane&15, g = lane>>4;           // MFMA fragment lane map
  // staging granule map (per thread, per rr): G = rr*256+tid
  int srow[2], schunk[2];
  #pragma unroll
  for (int rr=0; rr<2; ++rr){
    int G = rr*256 + tid;
    srow[rr]   = G>>2;
    schunk[rr] = ((G&3) - (srow[rr]>>1)) & 3;
  }
  const int rsw = (frow>>1)&3;                     // read-side rotation base
  f32x4 acc[4][4] = {};
  const int nt = K>>5;

  // prologue: stage tile 0 into buf 0
  #pragma unroll
  for (int rr=0; rr<2; ++rr){
    gl_lds16(A  + (size_t)(bm+srow[rr])*K + schunk[rr]*8,
             (char*)sA[0] + (rr*256 + wid*64)*16);
    gl_lds16(Bz + (size_t)(bn+srow[rr])*K + schunk[rr]*8,
             (char*)sB[0] + (rr*256 + wid*64)*16);
  }

  int buf = 0;
  for (int t = 0; t < nt; ++t){
    if (t+1 < nt){
      int k0 = (t+1)<<5;
      #pragma unroll
      for (int rr=0; rr<2; ++rr){
        gl_lds16(A  + (size_t)(bm+srow[rr])*K + k0 + schunk[rr]*8,
                 (char*)sA[buf^1] + (rr*256 + wid*64)*16);
        gl_lds16(Bz + (size_t)(bn+srow[rr])*K + k0 + schunk[rr]*8,
                 (char*)sB[buf^1] + (rr*256 + wid*64)*16);
      }
      asm volatile("s_waitcnt vmcnt(4)" ::: "memory");
    } else {
      asm volatile("s_waitcnt vmcnt(0)" ::: "memory");
    }
    __builtin_amdgcn_s_barrier();                  // all waves: buf ready
    bf16x8 a[4], b[4];
    const char* sAc = (const char*)sA[buf];
    const char* sBc = (const char*)sB[buf];
    #pragma unroll
    for (int m=0;m<4;++m)
      a[m] = *(const bf16x8*)(sAc + (wr*64+m*16+frow)*64 + (((g+rsw)&3)<<4));
    #pragma unroll
    for (int n=0;n<4;++n)
      b[n] = *(const bf16x8*)(sBc + (wc*64+n*16+frow)*64 + (((g+rsw)&3)<<4));
    #pragma unroll
    for (int m=0;m<4;++m)
      #pragma unroll
      for (int n=0;n<4;++n)
        acc[m][n] = __builtin_amdgcn_mfma_f32_16x16x32_bf16(a[m], b[n], acc[m][n], 0,0,0);
    __builtin_amdgcn_s_barrier();                  // all waves done reading buf
    buf ^= 1;
  }

  uint16_t* Oz = Obf + (size_t)z*(size_t)strideO;
  #pragma unroll
  for (int m=0;m<4;++m){
    int gr0 = bm + wr*64 + m*16 + (lane>>4)*4;     // C/D: col=lane&15, row=(lane>>4)*4+reg
    #pragma unroll
    for (int n=0;n<4;++n){
      int gc = bn + wc*64 + n*16 + (lane&15);
      #pragma unroll
      for (int r=0;r<4;++r){
        int grow = gr0 + r;
        float vsum = acc[m][n][r];
        if constexpr (MODE==EP_BF16){
          Oz[(size_t)grow*N + gc] = f2bf(vsum);
        } else if constexpr (MODE==EP_RES){
          X[(size_t)grow*N + gc] += vsum + bias[gc];
        } else if constexpr (MODE==EP_RELU){
          float u = vsum + bias[gc];
          Oz[(size_t)grow*N + gc] = f2bf(u > 0.f ? u : 0.f);
        } else {                                   // EP_EMB: token remap + pos
          int t2 = grow & 63, bb = grow >> 6;
          X[((size_t)bb*65 + 1 + t2)*768 + gc] = vsum + pos[(size_t)(t2+1)*768 + gc];
        }
      }
    }
  }
}

// ---------------- MFMA attention: one block (5 waves) per (b,head)
__global__ __launch_bounds__(320) void attn_mfma_k(const uint16_t* __restrict__ q,
    const uint16_t* __restrict__ k, const uint16_t* __restrict__ v,
    uint16_t* __restrict__ o)
{
  __shared__ __align__(16) uint16_t P_lds[80][104];  // queries x keys (pad 96+8)
  __shared__ __align__(16) uint16_t Vt[64][104];     // d x keys
  const int bh = blockIdx.x; const int b = bh / 12, hd = bh - b*12;
  const int tid = threadIdx.x;
  const int m = tid>>6;                              // wave id == query tile
  const int lane = tid&63;
  const int g = lane>>4, c = lane&15;
  const size_t base = (size_t)b*65*768 + (size_t)hd*64;

  // ---- zero LDS padding (keys >= 80 in P; keys 64..95 in Vt)
  for (int i = tid; i < 80*16; i += 320) P_lds[i>>4][80 + (i&15)] = 0;
  for (int i = tid; i < 64*32; i += 320) Vt[i>>5][64 + (i&31)] = 0;
  __syncthreads();
  // ---- transpose V into Vt: 65 keys x 8 d-chunks
  for (int j = tid; j < 520; j += 320){
    int key = j >> 3, dc = j & 7;
    union { bf16x8 v8; uint16_t u[8]; } gv;
    gv.v8 = *(const bf16x8*)&v[base + (size_t)key*768 + dc*8];
    #pragma unroll
    for (int e = 0; e < 8; ++e) Vt[dc*8 + e][key] = gv.u[e];
  }

  // ---- K fragments (B-operand: row = key = n*16+c, k-chunk = g*8)
  bf16x8 bk[5][2];
  #pragma unroll
  for (int n=0;n<5;++n)
    #pragma unroll
    for (int kk=0;kk<2;++kk)
      bk[n][kk] = *(const bf16x8*)&k[base + (size_t)(n*16 + c)*768 + kk*32 + g*8];

  // ---- S = Q K^T for this wave's query tile
  bf16x8 aq[2];
  #pragma unroll
  for (int kk=0;kk<2;++kk)
    aq[kk] = *(const bf16x8*)&q[base + (size_t)(m*16 + c)*768 + kk*32 + g*8];
  f32x4 sacc[5] = {};
  #pragma unroll
  for (int kk=0;kk<2;++kk)
    #pragma unroll
    for (int n=0;n<5;++n)
      sacc[n] = __builtin_amdgcn_mfma_f32_16x16x32_bf16(aq[kk], bk[n][kk], sacc[n], 0,0,0);

  // ---- in-register softmax (per output row r; 16-lane-group reduce)
  const float scale = 0.03608439182435161f;          // 768^-0.5
  #pragma unroll
  for (int r=0;r<4;++r){
    float val[5]; float mx = -3.0e38f;
    #pragma unroll
    for (int n=0;n<5;++n){
      val[n] = (n*16 + c) < 65 ? sacc[n][r]*scale : -3.0e38f;
      mx = fmaxf(mx, val[n]);
    }
    #pragma unroll
    for (int off=1; off<16; off<<=1) mx = fmaxf(mx, __shfl_xor(mx, off));
    float p[5], sum = 0.f;
    #pragma unroll
    for (int n=0;n<5;++n){
      p[n] = (n*16 + c) < 65 ? __expf(val[n]-mx) : 0.f;
      sum += p[n];
    }
    #pragma unroll
    for (int off=1; off<16; off<<=1) sum += __shfl_xor(sum, off);
    float rinv = 1.f / sum;
    int row = m*16 + g*4 + r;
    #pragma unroll
    for (int n=0;n<5;++n) P_lds[row][n*16 + c] = f2bf(p[n]*rinv);
  }
  __syncthreads();                                   // P + Vt ready

  // ---- O = P V  (A = P rows=query k=key; B = Vt rows=d k=key)
  bf16x8 vb[4][3];
  #pragma unroll
  for (int n=0;n<4;++n)
    #pragma unroll
    for (int kk=0;kk<3;++kk)
      vb[n][kk] = *(const bf16x8*)&Vt[n*16 + c][kk*32 + g*8];
  f32x4 oacc[4] = {};
  #pragma unroll
  for (int kk=0;kk<3;++kk){
    bf16x8 pa = *(const bf16x8*)&P_lds[m*16 + c][kk*32 + g*8];
    #pragma unroll
    for (int n=0;n<4;++n)
      oacc[n] = __builtin_amdgcn_mfma_f32_16x16x32_bf16(pa, vb[n][kk], oacc[n], 0,0,0);
  }
  #pragma unroll
  for (int r=0;r<4;++r){
    int row = m*16 + g*4 + r;
    if (row < 65){
      #pragma unroll
      for (int n=0;n<4;++n)
        o[base + (size_t)row*768 + n*16 + c] = f2bf(oacc[n][r]);
    }
  }
}

// ---------------- head: logits = cls @ head_w + b, softmax (all fp32)
__global__ __launch_bounds__(256) void head_k(const float* __restrict__ X,
    const float* __restrict__ W, const float* __restrict__ bias,
    float* __restrict__ out){
  int b = blockIdx.x, a = threadIdx.x;             // a in [0,256)
  const float* xr = X + (size_t)b*65*768;          // cls row
  float acc = bias[a];
  for (int kk=0; kk<768; ++kk) acc += xr[kk]*W[(size_t)kk*256 + a];
  int wid = a>>6, lane = a&63;
  __shared__ float red[4];
  float mx = acc;
  #pragma unroll
  for (int off=32; off; off>>=1) mx = fmaxf(mx, __shfl_xor(mx, off));
  if (lane==0) red[wid]=mx;
  __syncthreads();
  mx = fmaxf(fmaxf(red[0],red[1]), fmaxf(red[2],red[3]));
  float e = __expf(acc-mx);
  float s = e;
  #pragma unroll
  for (int off=32; off; off>>=1) s += __shfl_xor(s, off);
  __syncthreads();
  if (lane==0) red[wid]=s;
  __syncthreads();
  s = red[0]+red[1]+red[2]+red[3];
  out[(size_t)b*256 + a] = e/s;
}

// ============================================================================
extern "C" void kernel_launch(void* const* d_in, const int* in_sizes, int n_in,
                              void* d_out, int out_size, void* d_ws, size_t ws_size,
                              hipStream_t stream)
{
  const float* images = (const float*)d_in[0];
  const float* lin_w  = (const float*)d_in[1];
  const float* cls_tok= (const float*)d_in[2];
  const float* pos    = (const float*)d_in[3];
  const float* Wq = (const float*)d_in[4];
  const float* Wk = (const float*)d_in[5];
  const float* Wv = (const float*)d_in[6];
  const float* Wo = (const float*)d_in[7];
  const float* bo = (const float*)d_in[8];
  const float* ln1g=(const float*)d_in[9];
  const float* ln1b=(const float*)d_in[10];
  const float* ln2g=(const float*)d_in[11];
  const float* ln2b=(const float*)d_in[12];
  const float* W1 = (const float*)d_in[13];
  const float* b1 = (const float*)d_in[14];
  const float* W2 = (const float*)d_in[15];
  const float* b2 = (const float*)d_in[16];
  const float* hw = (const float*)d_in[17];
  const float* hb = (const float*)d_in[18];

  char* ws = (char*)d_ws;
  float*    x    = (float*)   (ws + 0);
  uint16_t* h    = (uint16_t*)(ws + 25559040);
  uint16_t* qkv  = (uint16_t*)(ws + 38338560);
  uint16_t* attn = (uint16_t*)(ws + 76677120);
  uint16_t* mid  = (uint16_t*)(ws + 89456640);     // patches alias
  uint16_t* wbuf = (uint16_t*)(ws + 140574720);
  uint16_t* lwt  = (uint16_t*)(ws + 154730496);

  // embed
  patchify_k<<<24576,256,0,stream>>>(images, mid);
  transpose_cvt_k<<<dim3(24,24),256,0,stream>>>(lin_w, lwt, 768, 768);
  gemm_bt_k<EP_EMB><<<dim3(6,64,1),256,0,stream>>>(mid, lwt, 8192,768,768, 0,0,
                                                   nullptr, x, nullptr, pos);
  cls_init_k<<<128,256,0,stream>>>(cls_tok, pos, x);

  for (int l=0;l<12;++l){
    prep_layer_k<<<6912,256,0,stream>>>(Wq+(size_t)l*589824, Wk+(size_t)l*589824,
                                        Wv+(size_t)l*589824, Wo+(size_t)l*589824,
                                        W1+(size_t)l*2359296, W2+(size_t)l*2359296, wbuf);
    ln_k<<<8320,256,0,stream>>>(x, h, ln1g+(size_t)l*768, ln1b+(size_t)l*768);
    gemm_bt_k<EP_BF16><<<dim3(6,65,3),256,0,stream>>>(h, wbuf, 8320,768,768,
                                                      589824, 6389760LL,
                                                      nullptr, nullptr, qkv, nullptr);
    attn_mfma_k<<<1536,320,0,stream>>>(qkv, qkv+6389760, qkv+12779520, attn);
    gemm_bt_k<EP_RES><<<dim3(6,65,1),256,0,stream>>>(attn, wbuf+1769472, 8320,768,768,
                                                     0,0, bo+(size_t)l*768, x, nullptr, nullptr);
    ln_k<<<8320,256,0,stream>>>(x, h, ln2g+(size_t)l*768, ln2b+(size_t)l*768);
    gemm_bt_k<EP_RELU><<<dim3(24,65,1),256,0,stream>>>(h, wbuf+2359296, 8320,3072,768,
                                                       0,0, b1+(size_t)l*3072, nullptr, mid, nullptr);
    gemm_bt_k<EP_RES><<<dim3(6,65,1),256,0,stream>>>(mid, wbuf+4718592, 8320,768,3072,
                                                     0,0, b2+(size_t)l*768, x, nullptr, nullptr);
  }
  head_k<<<128,256,0,stream>>>(x, hw, hb, (float*)d_out);
}

// Round 4
// 3267.793 us; speedup vs baseline: 1.6435x; 1.0868x over previous
//
#include <hip/hip_runtime.h>
#include <cstdint>
#include <cstddef>

// ============================================================================
// ViT forward, MI355X. Round 3: tile-size vs grid-starvation fix — BN=64 tiles
// for the 390-block GEMMs (Wo/MLP2/embed -> 780 blocks, 3 blocks/CU), bijective
// XCD swizzle on all GEMMs (A-panel L2 locality).
// Workspace layout unchanged (155,910,144 B).
// ============================================================================

typedef __bf16 bf16x8 __attribute__((ext_vector_type(8)));
typedef float  f32x4  __attribute__((ext_vector_type(4)));

#define DEVINL __device__ __forceinline__

DEVINL uint16_t f2bf(float f){
  union U{float f; uint32_t i;} v; v.f=f; uint32_t u=v.i;
  return (uint16_t)((u + 0x7fffu + ((u>>16)&1u)) >> 16);   // RNE
}

DEVINL void gl_lds16(const void* g, void* l){
  __builtin_amdgcn_global_load_lds((const __attribute__((address_space(1))) void*)g,
                                   (__attribute__((address_space(3))) void*)l, 16, 0, 0);
}

// ---------------- patchify: images (B,128,128,3) f32 -> patches (8192,768) bf16
__global__ __launch_bounds__(256) void patchify_k(const float* __restrict__ img,
                                                  uint16_t* __restrict__ out){
  int i = blockIdx.x*256 + threadIdx.x;            // 8192*768 = 6,291,456 exact
  int m  = i / 768, kk = i - m*768;
  int b  = m >> 6,  t  = m & 63;
  int py = t >> 3,  px = t & 7;
  int r  = kk / 48, rem = kk - r*48;               // rem = s*3+c (48 contiguous)
  size_t src = ((size_t)(b*128 + py*16 + r)*128 + px*16)*3 + rem;
  out[i] = f2bf(img[src]);
}

// ---------------- 32x32 transpose + f32->bf16 : src (R,C) f32 -> dst (C,R) bf16
DEVINL void tile_transpose(const float* __restrict__ src, uint16_t* __restrict__ dst,
                           int R, int C, int ti, int tj, int tid){
  __shared__ uint16_t tile[32][33];
  int tx = tid & 31, ty = tid >> 5;                // 32 x 8
  int r0 = ti*32, c0 = tj*32;
  #pragma unroll
  for (int i=0;i<4;++i)
    tile[ty+i*8][tx] = f2bf(src[(size_t)(r0+ty+i*8)*C + c0 + tx]);
  __syncthreads();
  #pragma unroll
  for (int i=0;i<4;++i)
    dst[(size_t)(c0+ty+i*8)*R + r0 + tx] = tile[tx][ty+i*8];
}

__global__ __launch_bounds__(256) void transpose_cvt_k(const float* __restrict__ src,
                                                       uint16_t* __restrict__ dst, int R, int C){
  tile_transpose(src, dst, R, C, blockIdx.y, blockIdx.x, threadIdx.x);
}

// one launch per layer: all 6 weights -> wbuf (B^T layout each)
__global__ __launch_bounds__(256) void prep_layer_k(
    const float* __restrict__ Wq, const float* __restrict__ Wk,
    const float* __restrict__ Wv, const float* __restrict__ Wo,
    const float* __restrict__ W1, const float* __restrict__ W2,
    uint16_t* __restrict__ wbuf){
  int idx = blockIdx.x;                            // 6912 tiles total
  const float* src; uint16_t* dst; int R, C, ti, tj;
  if (idx < 2304){                                 // Wq/Wk/Wv/Wo: (768,768)
    int m = idx / 576, t = idx - m*576; ti = t/24; tj = t - ti*24; R=768; C=768;
    src = (m==0)?Wq:(m==1)?Wk:(m==2)?Wv:Wo;
    dst = wbuf + (size_t)m*589824;
  } else if (idx < 4608){                          // W1: (768,3072) -> (3072,768)
    int t = idx - 2304; ti = t/96; tj = t - ti*96; R=768; C=3072;
    src = W1; dst = wbuf + 2359296;
  } else {                                         // W2: (3072,768) -> (768,3072)
    int t = idx - 4608; ti = t/24; tj = t - ti*24; R=3072; C=768;
    src = W2; dst = wbuf + 4718592;
  }
  tile_transpose(src, dst, R, C, ti, tj, threadIdx.x);
}

// ---------------- x[b,0,:] = cls_tok + pos_emb[0]
__global__ __launch_bounds__(256) void cls_init_k(const float* __restrict__ ct,
                                                  const float* __restrict__ pos,
                                                  float* __restrict__ X){
  int b = blockIdx.x, tid = threadIdx.x;
  for (int e = tid; e < 768; e += 256)
    X[(size_t)b*65*768 + e] = ct[e] + pos[e];
}

// ---------------- LayerNorm: x (rows,768) f32 -> h bf16 (two-pass, fp32)
__global__ __launch_bounds__(256) void ln_k(const float* __restrict__ Xin,
                                            uint16_t* __restrict__ H,
                                            const float* __restrict__ g,
                                            const float* __restrict__ b){
  int row = blockIdx.x, tid = threadIdx.x;
  const float* xr = Xin + (size_t)row*768;
  float v0 = xr[tid], v1 = xr[tid+256], v2 = xr[tid+512];
  int wid = tid>>6, lane = tid&63;
  __shared__ float part[4];
  __shared__ float bc[2];
  float s = v0+v1+v2;
  #pragma unroll
  for (int o=32;o;o>>=1) s += __shfl_down(s,o);
  if (lane==0) part[wid] = s;
  __syncthreads();
  if (tid==0) bc[0] = (part[0]+part[1]+part[2]+part[3]) * (1.f/768.f);
  __syncthreads();
  float mu = bc[0];
  float d0=v0-mu, d1=v1-mu, d2=v2-mu;
  float q = d0*d0 + d1*d1 + d2*d2;
  #pragma unroll
  for (int o=32;o;o>>=1) q += __shfl_down(q,o);
  __syncthreads();
  if (lane==0) part[wid] = q;
  __syncthreads();
  if (tid==0) bc[1] = rsqrtf((part[0]+part[1]+part[2]+part[3])*(1.f/768.f) + 1e-5f);
  __syncthreads();
  float rs = bc[1];
  uint16_t* hr = H + (size_t)row*768;
  hr[tid]     = f2bf(d0*rs*g[tid]     + b[tid]);
  hr[tid+256] = f2bf(d1*rs*g[tid+256] + b[tid+256]);
  hr[tid+512] = f2bf(d2*rs*g[tid+512] + b[tid+512]);
}

// ---------------- GEMM: C = A(M,K)bf16 @ Bt(N,K)bf16^T, fp32 acc, epilogues
// BM=128 fixed; BN templated (64 or 128). 4 waves (2M x 2N), wave tile
// 64 x BN/2. Double-buffered LDS, counted vmcnt, raw s_barrier, granule
// swizzle (write-side source permute + read-side rotation), XCD swizzle.
enum { EP_BF16=0, EP_RES=1, EP_RELU=2, EP_EMB=3 };

template<int MODE, int BN>
__global__ __launch_bounds__(256) void gemm_bt_k(
    const uint16_t* __restrict__ A, const uint16_t* __restrict__ Bt,
    int M, int N, int K, int strideB, long long strideO,
    const float* __restrict__ bias, float* __restrict__ X,
    uint16_t* __restrict__ Obf, const float* __restrict__ pos)
{
  constexpr int WN = BN/2;                         // wave N extent
  constexpr int NF = WN/16;                        // n fragments
  constexpr int BLOADS = BN/64;                    // B staging insts
  __shared__ __align__(16) uint16_t sA[2][128*32];
  __shared__ __align__(16) uint16_t sB[2][BN*32];
  const int tid = threadIdx.x;
  const int wid = tid>>6, lane = tid&63;
  // XCD-bijective swizzle of the flattened (x=N fastest) block index
  const int nx = gridDim.x;
  const int nwg = nx*gridDim.y;
  {
  }
  int idx = blockIdx.y*nx + blockIdx.x;
  int q8 = nwg>>3, r8 = nwg&7, xcd = idx&7, off = idx>>3;
  int swz = (xcd<r8 ? xcd*(q8+1) : r8*(q8+1) + (xcd-r8)*q8) + off;
  const int bn = (swz % nx)*BN, bm = (swz / nx)*128;
  const int z = blockIdx.z;
  const uint16_t* Bz = Bt + (size_t)z*strideB;
  const int wr = wid>>1, wc = wid&1;
  const int frow = lane&15, g = lane>>4;
  // staging granule maps (G -> row=G>>2, source chunk rotated by row>>1)
  int srA[2], scA[2];
  #pragma unroll
  for (int rr=0; rr<2; ++rr){
    int G = rr*256 + tid;
    srA[rr] = G>>2; scA[rr] = ((G&3) - (G>>3)) & 3;
  }
  int srB[2], scB[2];
  #pragma unroll
  for (int rr=0; rr<BLOADS; ++rr){
    int G = rr*256 + tid;
    srB[rr] = G>>2; scB[rr] = ((G&3) - (G>>3)) & 3;
  }
  const int rsw = (frow>>1)&3;                     // read-side rotation
  f32x4 acc[4][NF] = {};
  const int nt = K>>5;

  // prologue: stage tile 0 into buf 0
  #pragma unroll
  for (int rr=0; rr<2; ++rr)
    gl_lds16(A + (size_t)(bm+srA[rr])*K + scA[rr]*8, (char*)sA[0] + (rr*256 + wid*64)*16);
  #pragma unroll
  for (int rr=0; rr<BLOADS; ++rr)
    gl_lds16(Bz + (size_t)(bn+srB[rr])*K + scB[rr]*8, (char*)sB[0] + (rr*256 + wid*64)*16);

  int buf = 0;
  for (int t = 0; t < nt; ++t){
    if (t+1 < nt){
      int k0 = (t+1)<<5;
      #pragma unroll
      for (int rr=0; rr<2; ++rr)
        gl_lds16(A + (size_t)(bm+srA[rr])*K + k0 + scA[rr]*8,
                 (char*)sA[buf^1] + (rr*256 + wid*64)*16);
      #pragma unroll
      for (int rr=0; rr<BLOADS; ++rr)
        gl_lds16(Bz + (size_t)(bn+srB[rr])*K + k0 + scB[rr]*8,
                 (char*)sB[buf^1] + (rr*256 + wid*64)*16);
      if constexpr (BLOADS==1) asm volatile("s_waitcnt vmcnt(3)" ::: "memory");
      else                     asm volatile("s_waitcnt vmcnt(4)" ::: "memory");
    } else {
      asm volatile("s_waitcnt vmcnt(0)" ::: "memory");
    }
    __builtin_amdgcn_s_barrier();                  // buf ready
    bf16x8 a[4], b[NF];
    const char* sAc = (const char*)sA[buf];
    const char* sBc = (const char*)sB[buf];
    #pragma unroll
    for (int m=0;m<4;++m)
      a[m] = *(const bf16x8*)(sAc + (wr*64+m*16+frow)*64 + (((g+rsw)&3)<<4));
    #pragma unroll
    for (int n=0;n<NF;++n)
      b[n] = *(const bf16x8*)(sBc + (wc*WN+n*16+frow)*64 + (((g+rsw)&3)<<4));
    #pragma unroll
    for (int m=0;m<4;++m)
      #pragma unroll
      for (int n=0;n<NF;++n)
        acc[m][n] = __builtin_amdgcn_mfma_f32_16x16x32_bf16(a[m], b[n], acc[m][n], 0,0,0);
    __builtin_amdgcn_s_barrier();                  // done reading buf
    buf ^= 1;
  }

  uint16_t* Oz = Obf + (size_t)z*(size_t)strideO;
  #pragma unroll
  for (int m=0;m<4;++m){
    int gr0 = bm + wr*64 + m*16 + (lane>>4)*4;     // C/D: col=lane&15, row=(lane>>4)*4+reg
    #pragma unroll
    for (int n=0;n<NF;++n){
      int gc = bn + wc*WN + n*16 + (lane&15);
      #pragma unroll
      for (int r=0;r<4;++r){
        int grow = gr0 + r;
        float vsum = acc[m][n][r];
        if constexpr (MODE==EP_BF16){
          Oz[(size_t)grow*N + gc] = f2bf(vsum);
        } else if constexpr (MODE==EP_RES){
          X[(size_t)grow*N + gc] += vsum + bias[gc];
        } else if constexpr (MODE==EP_RELU){
          float u = vsum + bias[gc];
          Oz[(size_t)grow*N + gc] = f2bf(u > 0.f ? u : 0.f);
        } else {                                   // EP_EMB: token remap + pos
          int t2 = grow & 63, bb = grow >> 6;
          X[((size_t)bb*65 + 1 + t2)*768 + gc] = vsum + pos[(size_t)(t2+1)*768 + gc];
        }
      }
    }
  }
}

// ---------------- MFMA attention: one block (5 waves) per (b,head)
__global__ __launch_bounds__(320) void attn_mfma_k(const uint16_t* __restrict__ q,
    const uint16_t* __restrict__ k, const uint16_t* __restrict__ v,
    uint16_t* __restrict__ o)
{
  __shared__ __align__(16) uint16_t P_lds[80][104];  // queries x keys (pad 96+8)
  __shared__ __align__(16) uint16_t Vt[64][104];     // d x keys
  const int bh = blockIdx.x; const int b = bh / 12, hd = bh - b*12;
  const int tid = threadIdx.x;
  const int m = tid>>6;                              // wave id == query tile
  const int lane = tid&63;
  const int g = lane>>4, c = lane&15;
  const size_t base = (size_t)b*65*768 + (size_t)hd*64;

  // ---- zero LDS padding (keys >= 80 in P; keys 64..95 in Vt)
  for (int i = tid; i < 80*16; i += 320) P_lds[i>>4][80 + (i&15)] = 0;
  for (int i = tid; i < 64*32; i += 320) Vt[i>>5][64 + (i&31)] = 0;
  __syncthreads();
  // ---- transpose V into Vt: 65 keys x 8 d-chunks
  for (int j = tid; j < 520; j += 320){
    int key = j >> 3, dc = j & 7;
    union { bf16x8 v8; uint16_t u[8]; } gv;
    gv.v8 = *(const bf16x8*)&v[base + (size_t)key*768 + dc*8];
    #pragma unroll
    for (int e = 0; e < 8; ++e) Vt[dc*8 + e][key] = gv.u[e];
  }

  // ---- K fragments (B-operand: row = key = n*16+c, k-chunk = g*8)
  bf16x8 bk[5][2];
  #pragma unroll
  for (int n=0;n<5;++n)
    #pragma unroll
    for (int kk=0;kk<2;++kk)
      bk[n][kk] = *(const bf16x8*)&k[base + (size_t)(n*16 + c)*768 + kk*32 + g*8];

  // ---- S = Q K^T for this wave's query tile
  bf16x8 aq[2];
  #pragma unroll
  for (int kk=0;kk<2;++kk)
    aq[kk] = *(const bf16x8*)&q[base + (size_t)(m*16 + c)*768 + kk*32 + g*8];
  f32x4 sacc[5] = {};
  #pragma unroll
  for (int kk=0;kk<2;++kk)
    #pragma unroll
    for (int n=0;n<5;++n)
      sacc[n] = __builtin_amdgcn_mfma_f32_16x16x32_bf16(aq[kk], bk[n][kk], sacc[n], 0,0,0);

  // ---- in-register softmax (per output row r; 16-lane-group reduce)
  const float scale = 0.03608439182435161f;          // 768^-0.5
  #pragma unroll
  for (int r=0;r<4;++r){
    float val[5]; float mx = -3.0e38f;
    #pragma unroll
    for (int n=0;n<5;++n){
      val[n] = (n*16 + c) < 65 ? sacc[n][r]*scale : -3.0e38f;
      mx = fmaxf(mx, val[n]);
    }
    #pragma unroll
    for (int off=1; off<16; off<<=1) mx = fmaxf(mx, __shfl_xor(mx, off));
    float p[5], sum = 0.f;
    #pragma unroll
    for (int n=0;n<5;++n){
      p[n] = (n*16 + c) < 65 ? __expf(val[n]-mx) : 0.f;
      sum += p[n];
    }
    #pragma unroll
    for (int off=1; off<16; off<<=1) sum += __shfl_xor(sum, off);
    float rinv = 1.f / sum;
    int row = m*16 + g*4 + r;
    #pragma unroll
    for (int n=0;n<5;++n) P_lds[row][n*16 + c] = f2bf(p[n]*rinv);
  }
  __syncthreads();                                   // P + Vt ready

  // ---- O = P V  (A = P rows=query k=key; B = Vt rows=d k=key)
  bf16x8 vb[4][3];
  #pragma unroll
  for (int n=0;n<4;++n)
    #pragma unroll
    for (int kk=0;kk<3;++kk)
      vb[n][kk] = *(const bf16x8*)&Vt[n*16 + c][kk*32 + g*8];
  f32x4 oacc[4] = {};
  #pragma unroll
  for (int kk=0;kk<3;++kk){
    bf16x8 pa = *(const bf16x8*)&P_lds[m*16 + c][kk*32 + g*8];
    #pragma unroll
    for (int n=0;n<4;++n)
      oacc[n] = __builtin_amdgcn_mfma_f32_16x16x32_bf16(pa, vb[n][kk], oacc[n], 0,0,0);
  }
  #pragma unroll
  for (int r=0;r<4;++r){
    int row = m*16 + g*4 + r;
    if (row < 65){
      #pragma unroll
      for (int n=0;n<4;++n)
        o[base + (size_t)row*768 + n*16 + c] = f2bf(oacc[n][r]);
    }
  }
}

// ---------------- head: logits = cls @ head_w + b, softmax (all fp32)
__global__ __launch_bounds__(256) void head_k(const float* __restrict__ X,
    const float* __restrict__ W, const float* __restrict__ bias,
    float* __restrict__ out){
  int b = blockIdx.x, a = threadIdx.x;             // a in [0,256)
  const float* xr = X + (size_t)b*65*768;          // cls row
  float acc = bias[a];
  for (int kk=0; kk<768; ++kk) acc += xr[kk]*W[(size_t)kk*256 + a];
  int wid = a>>6, lane = a&63;
  __shared__ float red[4];
  float mx = acc;
  #pragma unroll
  for (int off=32; off; off>>=1) mx = fmaxf(mx, __shfl_xor(mx, off));
  if (lane==0) red[wid]=mx;
  __syncthreads();
  mx = fmaxf(fmaxf(red[0],red[1]), fmaxf(red[2],red[3]));
  float e = __expf(acc-mx);
  float s = e;
  #pragma unroll
  for (int off=32; off; off>>=1) s += __shfl_xor(s, off);
  __syncthreads();
  if (lane==0) red[wid]=s;
  __syncthreads();
  s = red[0]+red[1]+red[2]+red[3];
  out[(size_t)b*256 + a] = e/s;
}

// ============================================================================
extern "C" void kernel_launch(void* const* d_in, const int* in_sizes, int n_in,
                              void* d_out, int out_size, void* d_ws, size_t ws_size,
                              hipStream_t stream)
{
  const float* images = (const float*)d_in[0];
  const float* lin_w  = (const float*)d_in[1];
  const float* cls_tok= (const float*)d_in[2];
  const float* pos    = (const float*)d_in[3];
  const float* Wq = (const float*)d_in[4];
  const float* Wk = (const float*)d_in[5];
  const float* Wv = (const float*)d_in[6];
  const float* Wo = (const float*)d_in[7];
  const float* bo = (const float*)d_in[8];
  const float* ln1g=(const float*)d_in[9];
  const float* ln1b=(const float*)d_in[10];
  const float* ln2g=(const float*)d_in[11];
  const float* ln2b=(const float*)d_in[12];
  const float* W1 = (const float*)d_in[13];
  const float* b1 = (const float*)d_in[14];
  const float* W2 = (const float*)d_in[15];
  const float* b2 = (const float*)d_in[16];
  const float* hw = (const float*)d_in[17];
  const float* hb = (const float*)d_in[18];

  char* ws = (char*)d_ws;
  float*    x    = (float*)   (ws + 0);
  uint16_t* h    = (uint16_t*)(ws + 25559040);
  uint16_t* qkv  = (uint16_t*)(ws + 38338560);
  uint16_t* attn = (uint16_t*)(ws + 76677120);
  uint16_t* mid  = (uint16_t*)(ws + 89456640);     // patches alias
  uint16_t* wbuf = (uint16_t*)(ws + 140574720);
  uint16_t* lwt  = (uint16_t*)(ws + 154730496);

  // embed
  patchify_k<<<24576,256,0,stream>>>(images, mid);
  transpose_cvt_k<<<dim3(24,24),256,0,stream>>>(lin_w, lwt, 768, 768);
  gemm_bt_k<EP_EMB,64><<<dim3(12,64,1),256,0,stream>>>(mid, lwt, 8192,768,768, 0,0,
                                                   nullptr, x, nullptr, pos);
  cls_init_k<<<128,256,0,stream>>>(cls_tok, pos, x);

  for (int l=0;l<12;++l){
    prep_layer_k<<<6912,256,0,stream>>>(Wq+(size_t)l*589824, Wk+(size_t)l*589824,
                                        Wv+(size_t)l*589824, Wo+(size_t)l*589824,
                                        W1+(size_t)l*2359296, W2+(size_t)l*2359296, wbuf);
    ln_k<<<8320,256,0,stream>>>(x, h, ln1g+(size_t)l*768, ln1b+(size_t)l*768);
    gemm_bt_k<EP_BF16,128><<<dim3(6,65,3),256,0,stream>>>(h, wbuf, 8320,768,768,
                                                      589824, 6389760LL,
                                                      nullptr, nullptr, qkv, nullptr);
    attn_mfma_k<<<1536,320,0,stream>>>(qkv, qkv+6389760, qkv+12779520, attn);
    gemm_bt_k<EP_RES,64><<<dim3(12,65,1),256,0,stream>>>(attn, wbuf+1769472, 8320,768,768,
                                                     0,0, bo+(size_t)l*768, x, nullptr, nullptr);
    ln_k<<<8320,256,0,stream>>>(x, h, ln2g+(size_t)l*768, ln2b+(size_t)l*768);
    gemm_bt_k<EP_RELU,128><<<dim3(24,65,1),256,0,stream>>>(h, wbuf+2359296, 8320,3072,768,
                                                       0,0, b1+(size_t)l*3072, nullptr, mid, nullptr);
    gemm_bt_k<EP_RES,64><<<dim3(12,65,1),256,0,stream>>>(mid, wbuf+4718592, 8320,768,3072,
                                                     0,0, b2+(size_t)l*768, x, nullptr, nullptr);
  }
  head_k<<<128,256,0,stream>>>(x, hw, hb, (float*)d_out);
}